// Round 22
// baseline (71.312 us; speedup 1.0000x reference)
//
#include <hip/hip_runtime.h>

// LocalCrossCorrelation3D: I,J (2,1,96,192,192) fp32 -> (loss[2], cc[2,81,192,192])
// Window (16,9,9): depth valid (96->81), h/w zero-padded +-4.
// K1 = float2-ownership (each thread owns a w-pair -> dwordx2 loads, HALF the
// VMEM instructions/voxel), 2 rows per block (192 thr = 2 x 96), two-stage
// 3+3 w-box in float4 LDS, 2 raw barriers/od, ODPB=7 (2304 blocks, 9/CU).
// ws = AoS bf16 (12B/voxel). K2 = h sliding box, full unroll + static ring,
// CH=24, spread-slot loss atomics. K3 = slot reduce.

constexpr int N = 2, D = 96, H = 192, W = 192;
constexpr int OD = 81;            // D - 16 + 1
constexpr int KD = 16;
constexpr int HWp = H * W;        // 36864
constexpr int HW2 = HWp / 2;      // float2 stride
constexpr float INV_WIN = 1.0f / 1296.0f;
constexpr float EPS_NZ = 3.0590232050182579e-07f;  // e^-15
constexpr int CH = 24;            // h-chunk per block in K2 (192/24 = 8)
constexpr int ODPB = 7;           // od-range per K1 block (12 chunks, 9 blk/CU)

__device__ __forceinline__ unsigned bf16rne(float f) {  // f32 -> bf16 bits (RNE)
  unsigned u = __float_as_uint(f);
  return (u + 0x7fffu + ((u >> 16) & 1u)) >> 16;
}
__device__ __forceinline__ float bf16tof(unsigned h) {  // bf16 bits -> f32
  return __uint_as_float(h << 16);
}

// ---------------------------------------------------------------------------
// K1. Block = rows {2bx, 2bx+1} x all w. Thread (r, w2) owns cols c0=2*w2,
// c1=c0+1 of row r: float2 depth-stream loads. Per od:
//   snapshot 2 cols -> LDS x[r]; B1; stage1 a[c0]=x[c0-1]+x[c0]+x[c1],
//   a[c1]=x[c0]+x[c1]+x[c1+1] (own x in regs, 2 LDS reads); B2;
//   stage2 S[c]=a[c-3]+a[c]+a[c+3] (own a in regs, 4 LDS reads); pack+store.
// Hazard proof (single-buffered, 2 barriers/od): x-reads(od) drained by the
// lgkmcnt(0) before B2(od), x-write(od+1) after B2(od); a-reads(od) drained
// by lgkmcnt(0) before B1(od+1), a-write(od+1) after B1(od+1).
// Halo: x pads (cols -4..-1, 192..195) zeroed once; stage-1 halo positions
// (cols -3..-1 via w2<3, pe=w2+1; cols 192..194 via w2>=93, pe=w2+103).
// ws layout: [n][odi][h][w] x 3 uints (bf16 pairs: (s0,s1),(s2,s3),(s4,_)).
__global__ __launch_bounds__(192)
void k_dw(const float* __restrict__ I, const float* __restrict__ J,
          unsigned* __restrict__ ws, int od0, int c, int odcStride) {
  const int r  = threadIdx.x / 96;        // row within block (0/1)
  const int w2 = threadIdx.x % 96;        // thread-col (owns 2 cols)
  const int h  = 2 * blockIdx.x + r;
  const int n  = blockIdx.z;
  const int os = od0 + blockIdx.y * ODPB;
  int oe = od0 + c; if (os + ODPB < oe) oe = os + ODPB;
  if (os >= oe) return;

  __shared__ float4 x4[2][W + 8]; __shared__ float x1[2][W + 8];
  __shared__ float4 a4[2][W + 8]; __shared__ float a1[2][W + 8];

  if (threadIdx.x < 8) {   // zero x pads: pos 0..3 and 196..199, both rows
    const int pos = (threadIdx.x < 4) ? threadIdx.x : (192 + threadIdx.x);
    x4[0][pos] = make_float4(0.f,0.f,0.f,0.f); x1[0][pos] = 0.f;
    x4[1][pos] = make_float4(0.f,0.f,0.f,0.f); x1[1][pos] = 0.f;
  }
  __syncthreads();

  const int c0 = 2 * w2;
  const int p0 = 4 + c0;
  const size_t colBase = ((size_t)n * D * H + h) * (size_t)W + c0;
  const float2* Ip = (const float2*)(I + colBase);
  const float2* Jp = (const float2*)(J + colBase);
  unsigned* wbase = ws + ((size_t)n * odcStride * HWp + (size_t)h * W + c0) * 3;

  int pe = -1;
  if (w2 < 3) pe = w2 + 1;                // a-halo cols -3..-1
  else if (w2 >= 93) pe = w2 + 103;       // a-halo cols 192..194

  // warm-up: accumulate slices [os, os+KD-2] (15 slices)
  float2 sI = {0.f,0.f}, sJ = {0.f,0.f}, sII = {0.f,0.f},
         sJJ = {0.f,0.f}, sIJ = {0.f,0.f};
  for (int d = os; d < os + KD - 1; ++d) {
    const float2 iv = Ip[(size_t)d * HW2];
    const float2 jv = Jp[(size_t)d * HW2];
    sI.x += iv.x; sI.y += iv.y; sJ.x += jv.x; sJ.y += jv.y;
    sII.x += iv.x*iv.x; sII.y += iv.y*iv.y;
    sJJ.x += jv.x*jv.x; sJJ.y += jv.y*jv.y;
    sIJ.x += iv.x*jv.x; sIJ.y += iv.y*jv.y;
  }

  // prefetch first round: entering od+15, leaving od
  float2 eI = Ip[(size_t)(os + KD - 1) * HW2];
  float2 eJ = Jp[(size_t)(os + KD - 1) * HW2];
  float2 lI = Ip[(size_t)os * HW2];
  float2 lJ = Jp[(size_t)os * HW2];

  for (int od = os; od < oe; ++od) {
    const float2 ceI = eI, ceJ = eJ, clI = lI, clJ = lJ;
    const int odn = od + 1;
    if (odn < oe) {     // prefetch next round (awaited next iteration)
      eI = Ip[(size_t)(odn + KD - 1) * HW2];
      eJ = Jp[(size_t)(odn + KD - 1) * HW2];
      lI = Ip[(size_t)odn * HW2];
      lJ = Jp[(size_t)odn * HW2];
    }
    // snapshot both cols (post-add), keep copies in regs
    sI.x += ceI.x; sI.y += ceI.y; sJ.x += ceJ.x; sJ.y += ceJ.y;
    sII.x += ceI.x*ceI.x; sII.y += ceI.y*ceI.y;
    sJJ.x += ceJ.x*ceJ.x; sJJ.y += ceJ.y*ceJ.y;
    sIJ.x += ceI.x*ceJ.x; sIJ.y += ceI.y*ceJ.y;
    const float4 xc0 = make_float4(sI.x, sJ.x, sII.x, sJJ.x);
    const float4 xc1 = make_float4(sI.y, sJ.y, sII.y, sJJ.y);
    const float  xe0 = sIJ.x, xe1 = sIJ.y;
    x4[r][p0] = xc0;     x1[r][p0] = xe0;
    x4[r][p0+1] = xc1;   x1[r][p0+1] = xe1;
    sI.x -= clI.x; sI.y -= clI.y; sJ.x -= clJ.x; sJ.y -= clJ.y;
    sII.x -= clI.x*clI.x; sII.y -= clI.y*clI.y;
    sJJ.x -= clJ.x*clJ.x; sJJ.y -= clJ.y*clJ.y;
    sIJ.x -= clI.x*clJ.x; sIJ.y -= clI.y*clJ.y;

    asm volatile("s_waitcnt lgkmcnt(0)" ::: "memory");
    __builtin_amdgcn_s_barrier();       // B1: x visible
    // stage 1 (own x in regs; 2 neighbor reads)
    const float4 xm = x4[r][p0 - 1]; const float xme = x1[r][p0 - 1];
    const float4 xp = x4[r][p0 + 2]; const float xpe = x1[r][p0 + 2];
    const float4 aC0 = make_float4(xm.x + xc0.x + xc1.x, xm.y + xc0.y + xc1.y,
                                   xm.z + xc0.z + xc1.z, xm.w + xc0.w + xc1.w);
    const float  aE0 = xme + xe0 + xe1;
    const float4 aC1 = make_float4(xc0.x + xc1.x + xp.x, xc0.y + xc1.y + xp.y,
                                   xc0.z + xc1.z + xp.z, xc0.w + xc1.w + xp.w);
    const float  aE1 = xe0 + xe1 + xpe;
    a4[r][p0] = aC0;     a1[r][p0] = aE0;
    a4[r][p0+1] = aC1;   a1[r][p0+1] = aE1;
    if (pe >= 0) {      // halo a-position (3-tap fully from LDS)
      const float4 e0 = x4[r][pe - 1], e1 = x4[r][pe], e2 = x4[r][pe + 1];
      a4[r][pe] = make_float4(e0.x + e1.x + e2.x, e0.y + e1.y + e2.y,
                              e0.z + e1.z + e2.z, e0.w + e1.w + e2.w);
      a1[r][pe] = x1[r][pe - 1] + x1[r][pe] + x1[r][pe + 1];
    }
    asm volatile("s_waitcnt lgkmcnt(0)" ::: "memory");
    __builtin_amdgcn_s_barrier();       // B2: a visible
    // stage 2 (own a in regs; 4 neighbor reads)
    const float4 bm3 = a4[r][p0 - 3]; const float em3 = a1[r][p0 - 3];
    const float4 bp3 = a4[r][p0 + 3]; const float ep3 = a1[r][p0 + 3];
    const float4 bm2 = a4[r][p0 - 2]; const float em2 = a1[r][p0 - 2];
    const float4 bp4 = a4[r][p0 + 4]; const float ep4 = a1[r][p0 + 4];
    const float r0 = bm3.x + aC0.x + bp3.x;
    const float r1 = bm3.y + aC0.y + bp3.y;
    const float r2 = bm3.z + aC0.z + bp3.z;
    const float r3 = bm3.w + aC0.w + bp3.w;
    const float r4 = em3 + aE0 + ep3;
    const float q0 = bm2.x + aC1.x + bp4.x;
    const float q1 = bm2.y + aC1.y + bp4.y;
    const float q2 = bm2.z + aC1.z + bp4.z;
    const float q3 = bm2.w + aC1.w + bp4.w;
    const float q4 = em2 + aE1 + ep4;
    unsigned* o = wbase + (size_t)(od - od0) * HWp * 3;   // 6 u32, 8B aligned
    *(uint2*)(o)     = make_uint2(bf16rne(r0) | (bf16rne(r1) << 16),
                                  bf16rne(r2) | (bf16rne(r3) << 16));
    *(uint2*)(o + 2) = make_uint2(bf16rne(r4),
                                  bf16rne(q0) | (bf16rne(q1) << 16));
    *(uint2*)(o + 4) = make_uint2(bf16rne(q2) | (bf16rne(q3) << 16),
                                  bf16rne(q4));
  }
}

// ---------------------------------------------------------------------------
// K2: 9-wide h box via fully-unrolled stream with an 8-deep static ring
// (no subtract re-loads) + one-ahead prefetch; cc formula + loss reduction.
// Loss partial -> one of 32 spread slots per batch (atomic line-spread).
// Block: 192 threads = w-row, grid (od, h-chunk of 24, n).
__global__ __launch_bounds__(192)
void k_hcc(const unsigned* __restrict__ ws, float* __restrict__ cc,
           float* __restrict__ acc, int od0, int odcStride) {
  const int odi = blockIdx.x;
  const int od = od0 + odi;
  const int h0 = blockIdx.y * CH;
  const int n = blockIdx.z;
  const int w = threadIdx.x;
  const unsigned* base =
      ws + ((size_t)n * odcStride * HWp + (size_t)odi * HWp + w) * 3;
  float* ccp = cc + ((size_t)n * OD + od) * (size_t)HWp + w;

  float s0 = 0.f, s1 = 0.f, s2 = 0.f, s3 = 0.f, s4 = 0.f;
  float lsum = 0.f;
  uint3 hist[8];
  const uint3 z3 = make_uint3(0u, 0u, 0u);

  // prefetch t=0 row
  uint3 vN = z3;
  {
    const int hin = h0 - 4;
    if (hin >= 0) vN = *(const uint3*)(base + (size_t)hin * W * 3);
  }
#pragma unroll
  for (int t = 0; t < CH + 8; ++t) {
    const uint3 v = vN;
    // prefetch next row
    if (t + 1 < CH + 8) {
      const int hn = h0 - 4 + t + 1;
      vN = (hn >= 0 && hn < H) ? *(const uint3*)(base + (size_t)hn * W * 3) : z3;
    }
    s0 += bf16tof(v.x & 0xffffu); s1 += bf16tof(v.x >> 16);
    s2 += bf16tof(v.y & 0xffffu); s3 += bf16tof(v.y >> 16);
    s4 += bf16tof(v.z & 0xffffu);
    if (t >= 8) {
      const int h = h0 + t - 8;
      const float cross = s4 - s0 * s1 * INV_WIN;
      const float vI = s2 - s0 * s0 * INV_WIN;
      const float vJ = s3 - s1 * s1 * INV_WIN;
      const float prod = vI * vJ;
      const float c = (prod > EPS_NZ) ? (cross * cross) / (prod + EPS_NZ)
                                      : 1.0f / (1.0f + EPS_NZ);
      ccp[(size_t)h * W] = c;
      lsum += c;
      const uint3 q = hist[t & 7];       // row that entered 8 steps ago
      s0 -= bf16tof(q.x & 0xffffu); s1 -= bf16tof(q.x >> 16);
      s2 -= bf16tof(q.y & 0xffffu); s3 -= bf16tof(q.y >> 16);
      s4 -= bf16tof(q.z & 0xffffu);
    }
    hist[t & 7] = v;                     // static index (full unroll)
  }
  __shared__ float red[3];
#pragma unroll
  for (int off = 32; off > 0; off >>= 1) lsum += __shfl_xor(lsum, off, 64);
  if ((threadIdx.x & 63) == 0) red[threadIdx.x >> 6] = lsum;
  __syncthreads();
  if (threadIdx.x == 0)
    atomicAdd(acc + n * 32 + (odi & 31), red[0] + red[1] + red[2]);
}

// ---------------------------------------------------------------------------
// K3: reduce the 64 spread slots (32 per batch) -> loss.
__global__ void k_fin(const float* __restrict__ acc, float* __restrict__ out) {
  const int t = threadIdx.x;            // 64 threads
  float v = acc[t];                     // slots [n*32 + k]
#pragma unroll
  for (int off = 16; off > 0; off >>= 1) v += __shfl_xor(v, off, 32);
  if (t == 0)  out[0] = 1.0f - v * (1.0f / 2985984.0f);
  if (t == 32) out[1] = 1.0f - v * (1.0f / 2985984.0f);
}

// ---------------------------------------------------------------------------
extern "C" void kernel_launch(void* const* d_in, const int* in_sizes, int n_in,
                              void* d_out, int out_size, void* d_ws,
                              size_t ws_size, hipStream_t stream) {
  const float* I = (const float*)d_in[0];
  const float* J = (const float*)d_in[1];
  float* out = (float*)d_out;
  float* acc = (float*)d_ws;                       // 64 fp32 spread slots
  unsigned* planes = (unsigned*)((char*)d_ws + 256);

  hipMemsetAsync(d_ws, 0, 64 * sizeof(float), stream);

  // adaptive od-chunking: packed voxel = 12B, two n-slabs
  const size_t perOdPerN = (size_t)HWp * 12;       // 442368 B
  size_t avail = (ws_size > 256) ? (ws_size - 256) : 0;
  long long odcMax = (long long)(avail / (2 * perOdPerN));
  if (odcMax < 1) odcMax = 1;
  if (odcMax > OD) odcMax = OD;
  const int odc = (int)odcMax;                     // slab stride (od entries)

  float* ccOut = out + 2;
  for (int od0 = 0; od0 < OD; od0 += odc) {
    const int c = (odc < OD - od0) ? odc : (OD - od0);
    const int S = (c + ODPB - 1) / ODPB;
    hipLaunchKernelGGL(k_dw, dim3(H / 2, S, N), dim3(192), 0, stream,
                       I, J, planes, od0, c, odc);
    hipLaunchKernelGGL(k_hcc, dim3(c, H / CH, N), dim3(192), 0, stream,
                       planes, ccOut, acc, od0, odc);
  }
  hipLaunchKernelGGL(k_fin, dim3(1), dim3(64), 0, stream, acc, out);
}

// Round 23
// 64.444 us; speedup vs baseline: 1.1066x; 1.1066x over previous
//
#include <hip/hip_runtime.h>

// LocalCrossCorrelation3D: I,J (2,1,96,192,192) fp32 -> (loss[2], cc[2,81,192,192])
// Window (16,9,9): depth valid (96->81), h/w zero-padded +-4.
// BEST-MEASURED CONFIG (round 19, 63.8 us):
// K1 = depth sliding sum + two-stage 3+3 w-box in float4 LDS, two od-outputs
// per barrier round, raw barriers, 2-round-deep prefetch. ws = AoS uint3
// bf16 (12B/voxel).
// K2 = h sliding box, full unroll + static 8-deep ring, CH=24, spread-slot
// loss atomics. K3 = slot reduce.

constexpr int N = 2, D = 96, H = 192, W = 192;
constexpr int OD = 81;            // D - 16 + 1
constexpr int KD = 16;
constexpr int HWp = H * W;        // 36864
constexpr float INV_WIN = 1.0f / 1296.0f;
constexpr float EPS_NZ = 3.0590232050182579e-07f;  // e^-15
constexpr int CH = 24;            // h-chunk per block in K2 (192/24 = 8)
constexpr int ODPB = 14;          // od-range per K1 block (9 blocks/CU)

__device__ __forceinline__ unsigned bf16rne(float f) {  // f32 -> bf16 bits (RNE)
  unsigned u = __float_as_uint(f);
  return (u + 0x7fffu + ((u >> 16) & 1u)) >> 16;
}
__device__ __forceinline__ float bf16tof(unsigned h) {  // bf16 bits -> f32
  return __uint_as_float(h << 16);
}

// ---------------------------------------------------------------------------
// K1. Per (n,h) row, stream depth with running 5-ch sums; snapshots for od
// and od+1 go to LDS buffer sets 0/1; one {B1,stage1x2,B2,stage2x2} round
// serves both. TWO rounds of enter/leave slices prefetched (slots A/B).
// ws layout: [n][odi][h][w] x 3 uints (bf16 pairs: (s0,s1),(s2,s3),(s4,_)).
__global__ __launch_bounds__(192)
void k_dw(const float* __restrict__ I, const float* __restrict__ J,
          unsigned* __restrict__ ws, int od0, int c, int odcStride) {
  const int h = blockIdx.x;
  const int n = blockIdx.z;
  const int os = od0 + blockIdx.y * ODPB;
  int oe = od0 + c; if (os + ODPB < oe) oe = os + ODPB;
  if (os >= oe) return;
  const int w = threadIdx.x;

  __shared__ float4 x4[2][W + 8];
  __shared__ float  x1[2][W + 8];
  __shared__ float4 a4[2][W + 8];
  __shared__ float  a1[2][W + 8];

  if (w < 4) {
    x4[0][w] = make_float4(0.f,0.f,0.f,0.f); x1[0][w] = 0.f;
    x4[1][w] = make_float4(0.f,0.f,0.f,0.f); x1[1][w] = 0.f;
  }
  if (w >= W - 4) {
    x4[0][w + 8] = make_float4(0.f,0.f,0.f,0.f); x1[0][w + 8] = 0.f;
    x4[1][w + 8] = make_float4(0.f,0.f,0.f,0.f); x1[1][w + 8] = 0.f;
  }
  __syncthreads();   // one safe barrier before the pipelined loop

  const size_t colBase = ((size_t)n * D * H + h) * (size_t)W + w;
  const float* Ip = I + colBase;
  const float* Jp = J + colBase;
  unsigned* wbase = ws + ((size_t)n * odcStride * HWp + (size_t)h * W + w) * 3;

  // extra a3 position for halo coverage (pe in 1..3 and 196..198)
  int pe = -1;
  if (w < 3) pe = w + 1;
  else if (w >= W - 3) pe = w + 7;
  const int p = 4 + w;

  // warm-up: accumulate slices [os, os+KD-2] (15 slices)
  float sI = 0.f, sJ = 0.f, sII = 0.f, sJJ = 0.f, sIJ = 0.f;
  for (int d = os; d < os + KD - 1; ++d) {
    const float iv = Ip[(size_t)d * HWp];
    const float jv = Jp[(size_t)d * HWp];
    sI += iv; sJ += jv;
    sII += iv * iv; sJJ += jv * jv; sIJ += iv * jv;
  }

  // ISSUE loads for the round starting at od=O into the given slot vars.
#define ISSUE(eA,fA,gA,hA_,eB,fB,gB,hB_, O)                                  \
  { const int _o = (O);                                                      \
    if (_o < oe) {                                                           \
      eA = Ip[(size_t)(_o + KD - 1) * HWp];                                  \
      fA = Jp[(size_t)(_o + KD - 1) * HWp];                                  \
      gA = Ip[(size_t)_o * HWp];                                             \
      hA_ = Jp[(size_t)_o * HWp];                                            \
      if (_o + 1 < oe) {                                                     \
        eB = Ip[(size_t)(_o + KD) * HWp];                                    \
        fB = Jp[(size_t)(_o + KD) * HWp];                                    \
        gB = Ip[(size_t)(_o + 1) * HWp];                                     \
        hB_ = Jp[(size_t)(_o + 1) * HWp];                                    \
      } } }

  // COMPUTE the 2-od round at od=O, consuming the slot vars (by value).
#define COMPUTE(O, eA,fA,gA,hA_,eB,fB,gB,hB_)                                \
  { const int _od = (O);                                                     \
    const bool two = (_od + 1 < oe);                                         \
    sI += eA; sJ += fA;                                                      \
    sII += eA * eA; sJJ += fA * fA; sIJ += eA * fA;                          \
    x4[0][p] = make_float4(sI, sJ, sII, sJJ); x1[0][p] = sIJ;                \
    sI -= gA; sJ -= hA_;                                                     \
    sII -= gA * gA; sJJ -= hA_ * hA_; sIJ -= gA * hA_;                       \
    if (two) {                                                               \
      sI += eB; sJ += fB;                                                    \
      sII += eB * eB; sJJ += fB * fB; sIJ += eB * fB;                        \
      x4[1][p] = make_float4(sI, sJ, sII, sJJ); x1[1][p] = sIJ;              \
      sI -= gB; sJ -= hB_;                                                   \
      sII -= gB * gB; sJJ -= hB_ * hB_; sIJ -= gB * hB_;                     \
    }                                                                        \
    asm volatile("s_waitcnt lgkmcnt(0)" ::: "memory");                       \
    __builtin_amdgcn_s_barrier();       /* B1: x visible */                  \
    {                                                                        \
      float4 m0 = x4[0][p - 1], m1 = x4[0][p], m2 = x4[0][p + 1];            \
      a4[0][p] = make_float4(m0.x + m1.x + m2.x, m0.y + m1.y + m2.y,         \
                             m0.z + m1.z + m2.z, m0.w + m1.w + m2.w);        \
      a1[0][p] = x1[0][p - 1] + x1[0][p] + x1[0][p + 1];                     \
      if (pe >= 0) {                                                         \
        float4 e0 = x4[0][pe - 1], e1 = x4[0][pe], e2 = x4[0][pe + 1];       \
        a4[0][pe] = make_float4(e0.x + e1.x + e2.x, e0.y + e1.y + e2.y,      \
                                e0.z + e1.z + e2.z, e0.w + e1.w + e2.w);     \
        a1[0][pe] = x1[0][pe - 1] + x1[0][pe] + x1[0][pe + 1];               \
      }                                                                      \
    }                                                                        \
    if (two) {                                                               \
      float4 m0 = x4[1][p - 1], m1 = x4[1][p], m2 = x4[1][p + 1];            \
      a4[1][p] = make_float4(m0.x + m1.x + m2.x, m0.y + m1.y + m2.y,         \
                             m0.z + m1.z + m2.z, m0.w + m1.w + m2.w);        \
      a1[1][p] = x1[1][p - 1] + x1[1][p] + x1[1][p + 1];                     \
      if (pe >= 0) {                                                         \
        float4 e0 = x4[1][pe - 1], e1 = x4[1][pe], e2 = x4[1][pe + 1];       \
        a4[1][pe] = make_float4(e0.x + e1.x + e2.x, e0.y + e1.y + e2.y,      \
                                e0.z + e1.z + e2.z, e0.w + e1.w + e2.w);     \
        a1[1][pe] = x1[1][pe - 1] + x1[1][pe] + x1[1][pe + 1];               \
      }                                                                      \
    }                                                                        \
    asm volatile("s_waitcnt lgkmcnt(0)" ::: "memory");                       \
    __builtin_amdgcn_s_barrier();       /* B2: a visible */                  \
    {                                                                        \
      float4 b0 = a4[0][p - 3], b1 = a4[0][p], b2 = a4[0][p + 3];            \
      const float r0 = b0.x + b1.x + b2.x;                                   \
      const float r1 = b0.y + b1.y + b2.y;                                   \
      const float r2 = b0.z + b1.z + b2.z;                                   \
      const float r3 = b0.w + b1.w + b2.w;                                   \
      const float r4 = a1[0][p - 3] + a1[0][p] + a1[0][p + 3];               \
      unsigned* o = wbase + (size_t)(_od - od0) * HWp * 3;                   \
      *(uint3*)o = make_uint3(bf16rne(r0) | (bf16rne(r1) << 16),             \
                              bf16rne(r2) | (bf16rne(r3) << 16),             \
                              bf16rne(r4));                                  \
    }                                                                        \
    if (two) {                                                               \
      float4 b0 = a4[1][p - 3], b1 = a4[1][p], b2 = a4[1][p + 3];            \
      const float r0 = b0.x + b1.x + b2.x;                                   \
      const float r1 = b0.y + b1.y + b2.y;                                   \
      const float r2 = b0.z + b1.z + b2.z;                                   \
      const float r3 = b0.w + b1.w + b2.w;                                   \
      const float r4 = a1[1][p - 3] + a1[1][p] + a1[1][p + 3];               \
      unsigned* o = wbase + (size_t)(_od + 1 - od0) * HWp * 3;               \
      *(uint3*)o = make_uint3(bf16rne(r0) | (bf16rne(r1) << 16),             \
                              bf16rne(r2) | (bf16rne(r3) << 16),             \
                              bf16rne(r4));                                  \
    } }

  // 2-round-deep prefetch: slots A (even rounds) and B (odd rounds)
  float eA0=0,fA0=0,gA0=0,hA0=0, eA1=0,fA1=0,gA1=0,hA1=0;
  float eB0=0,fB0=0,gB0=0,hB0=0, eB1=0,fB1=0,gB1=0,hB1=0;
  ISSUE(eA0,fA0,gA0,hA0,eA1,fA1,gA1,hA1, os)
  ISSUE(eB0,fB0,gB0,hB0,eB1,fB1,gB1,hB1, os + 2)

  for (int od = os; od < oe; od += 4) {
    COMPUTE(od, eA0,fA0,gA0,hA0,eA1,fA1,gA1,hA1)
    ISSUE(eA0,fA0,gA0,hA0,eA1,fA1,gA1,hA1, od + 4)
    if (od + 2 < oe) {
      COMPUTE(od + 2, eB0,fB0,gB0,hB0,eB1,fB1,gB1,hB1)
      ISSUE(eB0,fB0,gB0,hB0,eB1,fB1,gB1,hB1, od + 6)
    }
  }
#undef ISSUE
#undef COMPUTE
}

// ---------------------------------------------------------------------------
// K2: 9-wide h box via fully-unrolled stream with an 8-deep static ring
// (no subtract re-loads) + one-ahead prefetch; cc formula + loss reduction.
// Loss partial -> one of 32 spread slots per batch (atomic line-spread).
// Block: 192 threads = w-row, grid (od, h-chunk of 24, n).
__global__ __launch_bounds__(192)
void k_hcc(const unsigned* __restrict__ ws, float* __restrict__ cc,
           float* __restrict__ acc, int od0, int odcStride) {
  const int odi = blockIdx.x;
  const int od = od0 + odi;
  const int h0 = blockIdx.y * CH;
  const int n = blockIdx.z;
  const int w = threadIdx.x;
  const unsigned* base =
      ws + ((size_t)n * odcStride * HWp + (size_t)odi * HWp + w) * 3;
  float* ccp = cc + ((size_t)n * OD + od) * (size_t)HWp + w;

  float s0 = 0.f, s1 = 0.f, s2 = 0.f, s3 = 0.f, s4 = 0.f;
  float lsum = 0.f;
  uint3 hist[8];
  const uint3 z3 = make_uint3(0u, 0u, 0u);

  // prefetch t=0 row
  uint3 vN = z3;
  {
    const int hin = h0 - 4;
    if (hin >= 0) vN = *(const uint3*)(base + (size_t)hin * W * 3);
  }
#pragma unroll
  for (int t = 0; t < CH + 8; ++t) {
    const uint3 v = vN;
    // prefetch next row
    if (t + 1 < CH + 8) {
      const int hn = h0 - 4 + t + 1;
      vN = (hn >= 0 && hn < H) ? *(const uint3*)(base + (size_t)hn * W * 3) : z3;
    }
    s0 += bf16tof(v.x & 0xffffu); s1 += bf16tof(v.x >> 16);
    s2 += bf16tof(v.y & 0xffffu); s3 += bf16tof(v.y >> 16);
    s4 += bf16tof(v.z & 0xffffu);
    if (t >= 8) {
      const int h = h0 + t - 8;
      const float cross = s4 - s0 * s1 * INV_WIN;
      const float vI = s2 - s0 * s0 * INV_WIN;
      const float vJ = s3 - s1 * s1 * INV_WIN;
      const float prod = vI * vJ;
      const float c = (prod > EPS_NZ) ? (cross * cross) / (prod + EPS_NZ)
                                      : 1.0f / (1.0f + EPS_NZ);
      ccp[(size_t)h * W] = c;
      lsum += c;
      const uint3 q = hist[t & 7];       // row that entered 8 steps ago
      s0 -= bf16tof(q.x & 0xffffu); s1 -= bf16tof(q.x >> 16);
      s2 -= bf16tof(q.y & 0xffffu); s3 -= bf16tof(q.y >> 16);
      s4 -= bf16tof(q.z & 0xffffu);
    }
    hist[t & 7] = v;                     // static index (full unroll)
  }
  __shared__ float red[3];
#pragma unroll
  for (int off = 32; off > 0; off >>= 1) lsum += __shfl_xor(lsum, off, 64);
  if ((threadIdx.x & 63) == 0) red[threadIdx.x >> 6] = lsum;
  __syncthreads();
  if (threadIdx.x == 0)
    atomicAdd(acc + n * 32 + (odi & 31), red[0] + red[1] + red[2]);
}

// ---------------------------------------------------------------------------
// K3: reduce the 64 spread slots (32 per batch) -> loss.
__global__ void k_fin(const float* __restrict__ acc, float* __restrict__ out) {
  const int t = threadIdx.x;            // 64 threads
  float v = acc[t];                     // slots [n*32 + k]
#pragma unroll
  for (int off = 16; off > 0; off >>= 1) v += __shfl_xor(v, off, 32);
  if (t == 0)  out[0] = 1.0f - v * (1.0f / 2985984.0f);
  if (t == 32) out[1] = 1.0f - v * (1.0f / 2985984.0f);
}

// ---------------------------------------------------------------------------
extern "C" void kernel_launch(void* const* d_in, const int* in_sizes, int n_in,
                              void* d_out, int out_size, void* d_ws,
                              size_t ws_size, hipStream_t stream) {
  const float* I = (const float*)d_in[0];
  const float* J = (const float*)d_in[1];
  float* out = (float*)d_out;
  float* acc = (float*)d_ws;                       // 64 fp32 spread slots
  unsigned* planes = (unsigned*)((char*)d_ws + 256);

  hipMemsetAsync(d_ws, 0, 64 * sizeof(float), stream);

  // adaptive od-chunking: packed voxel = 12B, two n-slabs
  const size_t perOdPerN = (size_t)HWp * 12;       // 442368 B
  size_t avail = (ws_size > 256) ? (ws_size - 256) : 0;
  long long odcMax = (long long)(avail / (2 * perOdPerN));
  if (odcMax < 1) odcMax = 1;
  if (odcMax > OD) odcMax = OD;
  const int odc = (int)odcMax;                     // slab stride (od entries)

  float* ccOut = out + 2;
  for (int od0 = 0; od0 < OD; od0 += odc) {
    const int c = (odc < OD - od0) ? odc : (OD - od0);
    const int S = (c + ODPB - 1) / ODPB;
    hipLaunchKernelGGL(k_dw, dim3(H, S, N), dim3(192), 0, stream,
                       I, J, planes, od0, c, odc);
    hipLaunchKernelGGL(k_hcc, dim3(c, H / CH, N), dim3(192), 0, stream,
                       planes, ccOut, acc, od0, odc);
  }
  hipLaunchKernelGGL(k_fin, dim3(1), dim3(64), 0, stream, acc, out);
}